// Round 9
// baseline (213.508 us; speedup 1.0000x reference)
//
#include <hip/hip_runtime.h>
#include <hip/hip_bf16.h>

#define BB 2
#define TT 2048
#define CCH 1024
#define NHH 16
#define HDD 64
#define M_TOK (BB*TT)      // 4096
#define N_QKV (3*CCH)      // 3072

typedef __attribute__((ext_vector_type(8))) short bf16x8;
typedef __attribute__((ext_vector_type(4))) float f32x4;
typedef unsigned short u16;
typedef unsigned int u32;

__device__ __forceinline__ u16 f2bf(float f) {
    union { float f; u32 u; } v; v.f = f;
    u32 u = v.u;
    u32 r = (u + 0x7FFFu + ((u >> 16) & 1u)) >> 16;
    return (u16)r;
}

// pack hi16(a),hi16(b) -> u32 {b.hi<<16 | a.hi} with +0x8000 rounding
__device__ __forceinline__ u32 pk_bf16(float a, float b) {
    u32 ua = __float_as_uint(a) + 0x8000u;
    u32 ub = __float_as_uint(b) + 0x8000u;
    return __builtin_amdgcn_perm(ub, ua, 0x07060302u);
}

__device__ __forceinline__ void async_copy16(const void* g, void* l) {
    __builtin_amdgcn_global_load_lds((__attribute__((address_space(1))) void*)g,
                                     (__attribute__((address_space(3))) void*)l,
                                     16, 0, 0);
}

// ---------------- pre-pass kernels ----------------

__global__ __launch_bounds__(256) void cast_bf16_kernel(
    const float* __restrict__ src, u16* __restrict__ dst, int n4) {
    int i = blockIdx.x * 256 + threadIdx.x;
    if (i < n4) {
        float4 f = ((const float4*)src)[i];
        ushort4 o;
        o.x = f2bf(f.x); o.y = f2bf(f.y); o.z = f2bf(f.z); o.w = f2bf(f.w);
        ((ushort4*)dst)[i] = o;
    }
}

// src [R][Cn] fp32 -> dst [Cn][R] bf16; rows of dst with index < scale_rows get *= sc
__global__ __launch_bounds__(256) void transpose_bf16_kernel(
    const float* __restrict__ src, u16* __restrict__ dst, int R, int Cn,
    int scale_rows, float sc) {
    __shared__ float tile[32][33];
    int c0 = blockIdx.x * 32, r0 = blockIdx.y * 32;
    int tx = threadIdx.x, ty = threadIdx.y;
#pragma unroll
    for (int i = ty; i < 32; i += 8)
        tile[i][tx] = src[(size_t)(r0 + i) * Cn + c0 + tx];
    __syncthreads();
#pragma unroll
    for (int i = ty; i < 32; i += 8) {
        float v = tile[tx][i];
        if (c0 + i < scale_rows) v *= sc;
        dst[(size_t)(c0 + i) * R + r0 + tx] = f2bf(v);
    }
}

// ---------------- GEMM (m97 structure): C[M][N] = A[M][K] * Bt[N][K]^T ----------------
// SWAP=1: mfma(B,A) -> C^T fragments: token on lane&15, 4 consecutive N-cols per lane.
// MODE 0 (SWAP=1): Cout fp32, float4 stores.
// MODE 1, SWAP=1: Q/K parts -> [bh][t][d] bf16, 8B stores along d.
// MODE 1, SWAP=0: V part -> Vt [bh][d][t] bf16, 8B stores along t.

template<int MODE, int SWAP>
__global__ __launch_bounds__(256) void gemm_bt_kernel(
    const u16* __restrict__ A, const u16* __restrict__ Bt,
    int M, int N, int K, int n_off,
    float* __restrict__ Cout,
    u16* __restrict__ Qo, u16* __restrict__ Ko, u16* __restrict__ Vto)
{
    __shared__ u16 As[128 * 32];
    __shared__ u16 Bs[128 * 32];
    int t = threadIdx.x;
    int m0 = blockIdx.y * 128, n0 = blockIdx.x * 128 + n_off;
    int lane = t & 63, w = t >> 6;
    int mw = (w >> 1) * 64, nw = (w & 1) * 64;
    int mr = lane & 15, quad = lane >> 4;

    f32x4 zero = {0.f, 0.f, 0.f, 0.f};
    f32x4 acc[4][4];
#pragma unroll
    for (int i = 0; i < 4; ++i)
#pragma unroll
        for (int j = 0; j < 4; ++j) acc[i][j] = zero;

    int rA = t >> 2, ko = (t & 3) << 3;
    const u16* gA0 = A + (size_t)(m0 + rA) * K + ko;
    const u16* gA1 = A + (size_t)(m0 + 64 + rA) * K + ko;
    const u16* gB0 = Bt + (size_t)(n0 + rA) * K + ko;
    const u16* gB1 = Bt + (size_t)(n0 + 64 + rA) * K + ko;
    u16* lA0 = As + (size_t)t * 8;
    u16* lA1 = As + (size_t)(256 + t) * 8;
    u16* lB0 = Bs + (size_t)t * 8;
    u16* lB1 = Bs + (size_t)(256 + t) * 8;

    for (int k0 = 0; k0 < K; k0 += 32) {
        async_copy16(gA0 + k0, lA0);
        async_copy16(gA1 + k0, lA1);
        async_copy16(gB0 + k0, lB0);
        async_copy16(gB1 + k0, lB1);
        __syncthreads();
        bf16x8 af[4], bfr[4];
#pragma unroll
        for (int i = 0; i < 4; ++i)
            af[i] = *(const bf16x8*)&As[(mw + i * 16 + mr) * 32 + quad * 8];
#pragma unroll
        for (int j = 0; j < 4; ++j)
            bfr[j] = *(const bf16x8*)&Bs[(nw + j * 16 + mr) * 32 + quad * 8];
#pragma unroll
        for (int i = 0; i < 4; ++i)
#pragma unroll
            for (int j = 0; j < 4; ++j) {
                if (SWAP)
                    acc[i][j] = __builtin_amdgcn_mfma_f32_16x16x32_bf16(bfr[j], af[i], acc[i][j], 0, 0, 0);
                else
                    acc[i][j] = __builtin_amdgcn_mfma_f32_16x16x32_bf16(af[i], bfr[j], acc[i][j], 0, 0, 0);
            }
        __syncthreads();
    }

    if (MODE == 0) {
        // SWAP=1: per (i,j): token = m0+mw+i*16+mr, cols cg0..cg0+3
#pragma unroll
        for (int i = 0; i < 4; ++i)
#pragma unroll
            for (int j = 0; j < 4; ++j) {
                int tok = m0 + mw + i * 16 + mr;
                int cg0 = n0 + nw + j * 16 + quad * 4;
                float4 v;
                v.x = acc[i][j][0]; v.y = acc[i][j][1];
                v.z = acc[i][j][2]; v.w = acc[i][j][3];
                *(float4*)&Cout[(size_t)tok * N + cg0] = v;
            }
    } else if (SWAP == 1) {
        // Q/K parts: [bh][t][d], 4 consecutive d per lane
        int part = n0 >> 10;
        u16* dstp = part ? Ko : Qo;
#pragma unroll
        for (int i = 0; i < 4; ++i)
#pragma unroll
            for (int j = 0; j < 4; ++j) {
                int tok = m0 + mw + i * 16 + mr;
                int cg0 = n0 + nw + j * 16 + quad * 4;
                int cc = cg0 & 1023;
                int h = cc >> 6, d0 = cc & 63;
                int b = tok >> 11, tt = tok & 2047;
                int bh = b * NHH + h;
                uint2 o;
                o.x = pk_bf16(acc[i][j][0], acc[i][j][1]);
                o.y = pk_bf16(acc[i][j][2], acc[i][j][3]);
                *(uint2*)&dstp[((size_t)bh * TT + tt) * HDD + d0] = o;
            }
    } else {
        // V part: Vt [bh][d][t], 4 consecutive t per lane
#pragma unroll
        for (int i = 0; i < 4; ++i)
#pragma unroll
            for (int j = 0; j < 4; ++j) {
                int t0 = m0 + mw + i * 16 + quad * 4;
                int cg = n0 + nw + j * 16 + mr;
                int cc = cg & 1023;
                int h = cc >> 6, d = cc & 63;
                int b = t0 >> 11, tt0 = t0 & 2047;
                int bh = b * NHH + h;
                uint2 o;
                o.x = pk_bf16(acc[i][j][0], acc[i][j][1]);
                o.y = pk_bf16(acc[i][j][2], acc[i][j][3]);
                *(uint2*)&Vto[((size_t)bh * HDD + d) * TT + tt0] = o;
            }
    }
}

// ---------------- flash attention v9 (= v7 structure + balanced pairing) ----------------
// K+V LDS staging (single-buffer, 2 barriers/chunk, 4-wave sharing),
// cheap softmax (no max-tracking, Q pre-scaled, deferred row-sum),
// complementary q-tile pairing with CONSTANT co-resident sum:
// pr = g<8 ? g : 23-g  ->  blocks (bid, bid+256) sum to 49 staging rounds.
// LDS = 8K (Ks) + 8K (Vs) + 9.2K (P) = 25.3 KB.

#define PSTRIDE 72

template<bool MASK>
__device__ __forceinline__ void tile_compute(
    const u16* __restrict__ Ks, const u16* __restrict__ Vs, u16* __restrict__ pb,
    bf16x8 qf0, bf16x8 qf1, int m, int quad, int qcol, int kv0,
    f32x4 (&o)[4], f32x4& ls)
{
    f32x4 zero = {0.f, 0.f, 0.f, 0.f};
    int sw = m & 7;
    // QK^T -> S^T: kv on quad*4+r (per kc), q on lane&15. K frags from swizzled LDS.
    f32x4 st[4];
#pragma unroll
    for (int kc = 0; kc < 4; ++kc) {
        int rr = kc * 16 + m;
        bf16x8 kf0 = *(const bf16x8*)&Ks[rr * 64 + ((quad ^ sw) << 3)];
        bf16x8 kf1 = *(const bf16x8*)&Ks[rr * 64 + (((quad + 4) ^ sw) << 3)];
        f32x4 s = __builtin_amdgcn_mfma_f32_16x16x32_bf16(kf0, qf0, zero, 0, 0, 0);
        st[kc]   = __builtin_amdgcn_mfma_f32_16x16x32_bf16(kf1, qf1, s, 0, 0, 0);
    }
    // exp2, partial row sums, pack -> wave-private P LDS [q][kv]
#pragma unroll
    for (int kc = 0; kc < 4; ++kc) {
        float e0, e1, e2, e3;
#pragma unroll
        for (int r = 0; r < 4; ++r) {
            float v = st[kc][r];
            if (MASK && (kv0 + kc * 16 + quad * 4 + r > qcol)) v = -1e30f;
            float e = __builtin_amdgcn_exp2f(v);
            ls[r] += e;
            if (r == 0) e0 = e; else if (r == 1) e1 = e; else if (r == 2) e2 = e; else e3 = e;
        }
        uint2 pk; pk.x = pk_bf16(e0, e1); pk.y = pk_bf16(e2, e3);
        *(uint2*)&pb[m * PSTRIDE + kc * 16 + quad * 4] = pk;
    }
    // PV: O^T += V^T-frag x P^T-frag; V frags from swizzled LDS
#pragma unroll
    for (int ks = 0; ks < 2; ++ks) {
        bf16x8 pf = *(const bf16x8*)&pb[m * PSTRIDE + ks * 32 + quad * 8];
#pragma unroll
        for (int dg = 0; dg < 4; ++dg) {
            int rr = dg * 16 + m;
            bf16x8 vfr = *(const bf16x8*)&Vs[rr * 64 + (((quad + 4 * ks) ^ sw) << 3)];
            o[dg] = __builtin_amdgcn_mfma_f32_16x16x32_bf16(vfr, pf, o[dg], 0, 0, 0);
        }
    }
}

__global__ __launch_bounds__(256) void attn_kernel(
    const u16* __restrict__ Q, const u16* __restrict__ K,
    const u16* __restrict__ Vt, u16* __restrict__ Y)
{
    __shared__ u16 Ks[64 * 64];
    __shared__ u16 Vs[64 * 64];
    __shared__ u16 Pl[4][16 * PSTRIDE];
    int t = threadIdx.x;
    int w = t >> 6, lane = t & 63;
    int m = lane & 15, quad = lane >> 4;

    int bid = blockIdx.x;
    int head = bid & 31;                 // head%8 = bid%8 -> XCD affinity
    int g = bid >> 5;                    // 0..15
    int pr = (g < 8) ? g : 23 - g;       // co-resident pair (bid, bid+256) sums const
    int qbA = pr;                        // light q-block (chunks 0..qbA)
    int qbB = 31 - pr;                   // heavy q-block (chunks 0..qbB)
    int rowA = qbA * 64 + w * 16;
    int rowB = qbB * 64 + w * 16;

    const u16* qpA = Q + ((size_t)head * TT + rowA + m) * HDD + quad * 8;
    const u16* qpB = Q + ((size_t)head * TT + rowB + m) * HDD + quad * 8;
    bf16x8 qA0 = *(const bf16x8*)qpA;
    bf16x8 qA1 = *(const bf16x8*)(qpA + 32);
    bf16x8 qB0 = *(const bf16x8*)qpB;
    bf16x8 qB1 = *(const bf16x8*)(qpB + 32);

    const u16* kbase = K + (size_t)head * TT * HDD;   // [t][d]
    const u16* vbase = Vt + (size_t)head * HDD * TT;  // [d][t]
    u16* pb = &Pl[w][0];

    // staging geometry (lane-contiguous LDS, XOR swizzle on global col-group)
    int lr = lane >> 3;
    int cg = (lane & 7) ^ lr;
    int r0 = w * 16 + lr, r1 = r0 + 8;
    u16* ldsK0 = Ks + (size_t)(w * 128 + lane) * 8;
    u16* ldsK1 = Ks + (size_t)(w * 128 + 64 + lane) * 8;
    u16* ldsV0 = Vs + (size_t)(w * 128 + lane) * 8;
    u16* ldsV1 = Vs + (size_t)(w * 128 + 64 + lane) * 8;

    f32x4 zero = {0.f, 0.f, 0.f, 0.f};
    f32x4 oA[4], oB[4], lsA = zero, lsB = zero;
#pragma unroll
    for (int dg = 0; dg < 4; ++dg) { oA[dg] = zero; oB[dg] = zero; }
    int qcolA = rowA + m, qcolB = rowB + m;

    for (int ic = 0; ic <= qbB; ++ic) {
        int kv0 = ic << 6;
        async_copy16(kbase + (size_t)(kv0 + r0) * 64 + cg * 8, ldsK0);
        async_copy16(kbase + (size_t)(kv0 + r1) * 64 + cg * 8, ldsK1);
        async_copy16(vbase + (size_t)r0 * TT + kv0 + cg * 8, ldsV0);
        async_copy16(vbase + (size_t)r1 * TT + kv0 + cg * 8, ldsV1);
        __syncthreads();            // staged chunk arrived
        if (ic < qbA)
            tile_compute<false>(Ks, Vs, pb, qA0, qA1, m, quad, qcolA, kv0, oA, lsA);
        else if (ic == qbA)
            tile_compute<true>(Ks, Vs, pb, qA0, qA1, m, quad, qcolA, kv0, oA, lsA);
        if (ic < qbB)
            tile_compute<false>(Ks, Vs, pb, qB0, qB1, m, quad, qcolB, kv0, oB, lsB);
        else
            tile_compute<true>(Ks, Vs, pb, qB0, qB1, m, quad, qcolB, kv0, oB, lsB);
        __syncthreads();            // all waves done before restage
    }

    // row-sum reduce (q on lane&15; partials across quad groups)
    float lA = (lsA[0] + lsA[1]) + (lsA[2] + lsA[3]);
    float lB = (lsB[0] + lsB[1]) + (lsB[2] + lsB[3]);
    lA += __shfl_xor(lA, 16, 64); lA += __shfl_xor(lA, 32, 64);
    lB += __shfl_xor(lB, 16, 64); lB += __shfl_xor(lB, 32, 64);
    float invA = 1.0f / lA, invB = 1.0f / lB;

    int b = head >> 4, h = head & 15;
    size_t roA = ((size_t)(b * TT + rowA + m)) * CCH + h * HDD;
    size_t roB = ((size_t)(b * TT + rowB + m)) * CCH + h * HDD;
#pragma unroll
    for (int dg = 0; dg < 4; ++dg) {
        uint2 ov;
        ov.x = pk_bf16(oA[dg][0] * invA, oA[dg][1] * invA);
        ov.y = pk_bf16(oA[dg][2] * invA, oA[dg][3] * invA);
        *(uint2*)&Y[roA + dg * 16 + quad * 4] = ov;
        ov.x = pk_bf16(oB[dg][0] * invB, oB[dg][1] * invB);
        ov.y = pk_bf16(oB[dg][2] * invB, oB[dg][3] * invB);
        *(uint2*)&Y[roB + dg * 16 + quad * 4] = ov;
    }
}

// ---------------- launch ----------------

extern "C" void kernel_launch(void* const* d_in, const int* in_sizes, int n_in,
                              void* d_out, int out_size, void* d_ws, size_t ws_size,
                              hipStream_t stream) {
    const float* x      = (const float*)d_in[0];
    const float* w_attn = (const float*)d_in[1];
    const float* w_proj = (const float*)d_in[2];
    float* out = (float*)d_out;

    char* ws = (char*)d_ws;
    u16* x_bf   = (u16*)ws; ws += (size_t)M_TOK * CCH * 2;         // 8 MB
    u16* wqkvT  = (u16*)ws; ws += (size_t)N_QKV * CCH * 2;         // 6 MB
    u16* wprojT = (u16*)ws; ws += (size_t)CCH * CCH * 2;           // 2 MB
    u16* qbuf   = (u16*)ws; ws += (size_t)BB * NHH * TT * HDD * 2; // 8 MB
    u16* kbuf   = (u16*)ws; ws += (size_t)BB * NHH * TT * HDD * 2; // 8 MB
    u16* vtb    = (u16*)ws; ws += (size_t)BB * NHH * HDD * TT * 2; // 8 MB
    u16* yb     = (u16*)ws; ws += (size_t)M_TOK * CCH * 2;         // 8 MB

    // softmax scale * log2(e), folded into Q columns of w_attn during transpose
    const float QSC = 0.125f * 1.44269504088896f;

    // 1. cast x -> bf16
    cast_bf16_kernel<<<dim3(M_TOK * CCH / 4 / 256), dim3(256), 0, stream>>>(x, x_bf, M_TOK * CCH / 4);
    // 2. transpose weights -> bf16 [N][K]
    transpose_bf16_kernel<<<dim3(N_QKV / 32, CCH / 32), dim3(32, 8), 0, stream>>>(
        w_attn, wqkvT, CCH, N_QKV, CCH, QSC);
    transpose_bf16_kernel<<<dim3(CCH / 32, CCH / 32), dim3(32, 8), 0, stream>>>(
        w_proj, wprojT, CCH, CCH, 0, 1.0f);
    // 3a. QKV GEMM, Q/K parts (swapped orientation -> [bh][t][d] with 8B stores)
    gemm_bt_kernel<1, 1><<<dim3(16, M_TOK / 128), dim3(256), 0, stream>>>(
        x_bf, wqkvT, M_TOK, N_QKV, CCH, 0, nullptr, qbuf, kbuf, nullptr);
    // 3b. QKV GEMM, V part (normal orientation -> Vt [bh][d][t] with 8B stores)
    gemm_bt_kernel<1, 0><<<dim3(8, M_TOK / 128), dim3(256), 0, stream>>>(
        x_bf, wqkvT, M_TOK, N_QKV, CCH, 2048, nullptr, nullptr, nullptr, vtb);
    // 4. flash attention v9 (v7 structure + balanced pairing)
    attn_kernel<<<dim3(512), dim3(256), 0, stream>>>(qbuf, kbuf, vtb, yb);
    // 5. output projection (swapped orientation -> float4 stores)
    gemm_bt_kernel<0, 1><<<dim3(8, M_TOK / 128), dim3(256), 0, stream>>>(
        yb, wprojT, M_TOK, CCH, CCH, 0, out, nullptr, nullptr, nullptr);
}

// Round 10
// 196.739 us; speedup vs baseline: 1.0852x; 1.0852x over previous
//
#include <hip/hip_runtime.h>
#include <hip/hip_bf16.h>

#define BB 2
#define TT 2048
#define CCH 1024
#define NHH 16
#define HDD 64
#define M_TOK (BB*TT)      // 4096
#define N_QKV (3*CCH)      // 3072

typedef __attribute__((ext_vector_type(8))) short bf16x8;
typedef __attribute__((ext_vector_type(4))) float f32x4;
typedef unsigned short u16;
typedef unsigned int u32;

__device__ __forceinline__ u16 f2bf(float f) {
    union { float f; u32 u; } v; v.f = f;
    u32 u = v.u;
    u32 r = (u + 0x7FFFu + ((u >> 16) & 1u)) >> 16;
    return (u16)r;
}

// pack hi16(a),hi16(b) -> u32 {b.hi<<16 | a.hi} with +0x8000 rounding
__device__ __forceinline__ u32 pk_bf16(float a, float b) {
    u32 ua = __float_as_uint(a) + 0x8000u;
    u32 ub = __float_as_uint(b) + 0x8000u;
    return __builtin_amdgcn_perm(ub, ua, 0x07060302u);
}

__device__ __forceinline__ void async_copy16(const void* g, void* l) {
    __builtin_amdgcn_global_load_lds((__attribute__((address_space(1))) void*)g,
                                     (__attribute__((address_space(3))) void*)l,
                                     16, 0, 0);
}

// ---------------- pre-pass kernels ----------------

__global__ __launch_bounds__(256) void cast_bf16_kernel(
    const float* __restrict__ src, u16* __restrict__ dst, int n4) {
    int i = blockIdx.x * 256 + threadIdx.x;
    if (i < n4) {
        float4 f = ((const float4*)src)[i];
        ushort4 o;
        o.x = f2bf(f.x); o.y = f2bf(f.y); o.z = f2bf(f.z); o.w = f2bf(f.w);
        ((ushort4*)dst)[i] = o;
    }
}

// src [R][Cn] fp32 -> dst [Cn][R] bf16; rows of dst with index < scale_rows get *= sc
__global__ __launch_bounds__(256) void transpose_bf16_kernel(
    const float* __restrict__ src, u16* __restrict__ dst, int R, int Cn,
    int scale_rows, float sc) {
    __shared__ float tile[32][33];
    int c0 = blockIdx.x * 32, r0 = blockIdx.y * 32;
    int tx = threadIdx.x, ty = threadIdx.y;
#pragma unroll
    for (int i = ty; i < 32; i += 8)
        tile[i][tx] = src[(size_t)(r0 + i) * Cn + c0 + tx];
    __syncthreads();
#pragma unroll
    for (int i = ty; i < 32; i += 8) {
        float v = tile[tx][i];
        if (c0 + i < scale_rows) v *= sc;
        dst[(size_t)(c0 + i) * R + r0 + tx] = f2bf(v);
    }
}

// ---------------- shared GEMM K-loop (m97 structure) ----------------
// A[M][K] x Bt[N][K]^T, 128-row M-tile, NJ*32-row N-tile (NJ=4 -> 128, NJ=2 -> 64).
// SWAP=1: mfma(B,A) -> acc holds C^T fragment (token on lane&15, cols on regs).

template<int SWAP, int NJ>
__device__ __forceinline__ void gemm_kloop(
    const u16* __restrict__ A, const u16* __restrict__ Bt, int K,
    int m0, int n0, int t, u16* __restrict__ As, u16* __restrict__ Bs,
    f32x4 (&acc)[4][4])
{
    int lane = t & 63, w = t >> 6;
    int mw = (w >> 1) * 64, nw = (w & 1) * (NJ * 16);
    int mr = lane & 15, quad = lane >> 4;

    int rA = t >> 2, ko = (t & 3) << 3;
    const u16* gA0 = A + (size_t)(m0 + rA) * K + ko;
    const u16* gA1 = A + (size_t)(m0 + 64 + rA) * K + ko;
    const u16* gB0 = Bt + (size_t)(n0 + rA) * K + ko;
    const u16* gB1 = (NJ == 4) ? Bt + (size_t)(n0 + 64 + rA) * K + ko : nullptr;
    u16* lA0 = As + (size_t)t * 8;
    u16* lA1 = As + (size_t)(256 + t) * 8;
    u16* lB0 = Bs + (size_t)t * 8;
    u16* lB1 = Bs + (size_t)(256 + t) * 8;

    for (int k0 = 0; k0 < K; k0 += 32) {
        async_copy16(gA0 + k0, lA0);
        async_copy16(gA1 + k0, lA1);
        async_copy16(gB0 + k0, lB0);
        if (NJ == 4) async_copy16(gB1 + k0, lB1);
        __syncthreads();
        bf16x8 af[4], bfr[NJ];
#pragma unroll
        for (int i = 0; i < 4; ++i)
            af[i] = *(const bf16x8*)&As[(mw + i * 16 + mr) * 32 + quad * 8];
#pragma unroll
        for (int j = 0; j < NJ; ++j)
            bfr[j] = *(const bf16x8*)&Bs[(nw + j * 16 + mr) * 32 + quad * 8];
#pragma unroll
        for (int i = 0; i < 4; ++i)
#pragma unroll
            for (int j = 0; j < NJ; ++j) {
                if (SWAP)
                    acc[i][j] = __builtin_amdgcn_mfma_f32_16x16x32_bf16(bfr[j], af[i], acc[i][j], 0, 0, 0);
                else
                    acc[i][j] = __builtin_amdgcn_mfma_f32_16x16x32_bf16(af[i], bfr[j], acc[i][j], 0, 0, 0);
            }
        __syncthreads();
    }
}

// ---------------- merged QKV GEMM: one 768-block dispatch ----------------
// Parts 0/1 (Q/K): swapped loop -> [bh][t][d] bf16, 8B stores along d.
// Part 2 (V): normal loop -> Vt [bh][d][t] bf16, 8B stores along t.

__global__ __launch_bounds__(256) void qkv_gemm_kernel(
    const u16* __restrict__ A, const u16* __restrict__ Bt,
    u16* __restrict__ Qo, u16* __restrict__ Ko, u16* __restrict__ Vto)
{
    __shared__ u16 As[128 * 32];
    __shared__ u16 Bs[128 * 32];
    int t = threadIdx.x;
    int m0 = blockIdx.y * 128, n0 = blockIdx.x * 128;
    int part = n0 >> 10;
    int lane = t & 63, w = t >> 6;
    int mw = (w >> 1) * 64, nw = (w & 1) * 64;
    int mr = lane & 15, quad = lane >> 4;

    f32x4 zero = {0.f, 0.f, 0.f, 0.f};
    f32x4 acc[4][4];
#pragma unroll
    for (int i = 0; i < 4; ++i)
#pragma unroll
        for (int j = 0; j < 4; ++j) acc[i][j] = zero;

    if (part < 2) {   // block-uniform branch
        gemm_kloop<1, 4>(A, Bt, CCH, m0, n0, t, As, Bs, acc);
        u16* dstp = part ? Ko : Qo;
#pragma unroll
        for (int i = 0; i < 4; ++i)
#pragma unroll
            for (int j = 0; j < 4; ++j) {
                int tok = m0 + mw + i * 16 + mr;
                int cg0 = n0 + nw + j * 16 + quad * 4;
                int cc = cg0 & 1023;
                int h = cc >> 6, d0 = cc & 63;
                int b = tok >> 11, tt = tok & 2047;
                int bh = b * NHH + h;
                uint2 o;
                o.x = pk_bf16(acc[i][j][0], acc[i][j][1]);
                o.y = pk_bf16(acc[i][j][2], acc[i][j][3]);
                *(uint2*)&dstp[((size_t)bh * TT + tt) * HDD + d0] = o;
            }
    } else {
        gemm_kloop<0, 4>(A, Bt, CCH, m0, n0, t, As, Bs, acc);
#pragma unroll
        for (int i = 0; i < 4; ++i)
#pragma unroll
            for (int j = 0; j < 4; ++j) {
                int t0 = m0 + mw + i * 16 + quad * 4;
                int cg = n0 + nw + j * 16 + mr;
                int cc = cg & 1023;
                int h = cc >> 6, d = cc & 63;
                int b = t0 >> 11, tt0 = t0 & 2047;
                int bh = b * NHH + h;
                uint2 o;
                o.x = pk_bf16(acc[i][j][0], acc[i][j][1]);
                o.y = pk_bf16(acc[i][j][2], acc[i][j][3]);
                *(uint2*)&Vto[((size_t)bh * HDD + d) * TT + tt0] = o;
            }
    }
}

// ---------------- output projection: 128x64 tiles, 512 blocks (2/CU) ----------------

__global__ __launch_bounds__(256) void proj_gemm_kernel(
    const u16* __restrict__ A, const u16* __restrict__ Bt, float* __restrict__ Cout)
{
    __shared__ u16 As[128 * 32];
    __shared__ u16 Bs[64 * 32];
    int t = threadIdx.x;
    int m0 = blockIdx.y * 128, n0 = blockIdx.x * 64;
    int lane = t & 63, w = t >> 6;
    int mw = (w >> 1) * 64, nw = (w & 1) * 32;
    int mr = lane & 15, quad = lane >> 4;

    f32x4 zero = {0.f, 0.f, 0.f, 0.f};
    f32x4 acc[4][4];
#pragma unroll
    for (int i = 0; i < 4; ++i)
#pragma unroll
        for (int j = 0; j < 4; ++j) acc[i][j] = zero;

    gemm_kloop<1, 2>(A, Bt, CCH, m0, n0, t, As, Bs, acc);

#pragma unroll
    for (int i = 0; i < 4; ++i)
#pragma unroll
        for (int j = 0; j < 2; ++j) {
            int tok = m0 + mw + i * 16 + mr;
            int cg0 = n0 + nw + j * 16 + quad * 4;
            float4 v;
            v.x = acc[i][j][0]; v.y = acc[i][j][1];
            v.z = acc[i][j][2]; v.w = acc[i][j][3];
            *(float4*)&Cout[(size_t)tok * CCH + cg0] = v;
        }
}

// ---------------- flash attention v9 (unchanged from round 9) ----------------
// K+V LDS staging (single-buffer, 2 barriers/chunk, 4-wave sharing),
// cheap softmax (no max-tracking, Q pre-scaled, deferred row-sum),
// complementary q-tile pairing with CONSTANT co-resident sum.
// LDS = 8K (Ks) + 8K (Vs) + 9.2K (P) = 25.3 KB.

#define PSTRIDE 72

template<bool MASK>
__device__ __forceinline__ void tile_compute(
    const u16* __restrict__ Ks, const u16* __restrict__ Vs, u16* __restrict__ pb,
    bf16x8 qf0, bf16x8 qf1, int m, int quad, int qcol, int kv0,
    f32x4 (&o)[4], f32x4& ls)
{
    f32x4 zero = {0.f, 0.f, 0.f, 0.f};
    int sw = m & 7;
    // QK^T -> S^T: kv on quad*4+r (per kc), q on lane&15. K frags from swizzled LDS.
    f32x4 st[4];
#pragma unroll
    for (int kc = 0; kc < 4; ++kc) {
        int rr = kc * 16 + m;
        bf16x8 kf0 = *(const bf16x8*)&Ks[rr * 64 + ((quad ^ sw) << 3)];
        bf16x8 kf1 = *(const bf16x8*)&Ks[rr * 64 + (((quad + 4) ^ sw) << 3)];
        f32x4 s = __builtin_amdgcn_mfma_f32_16x16x32_bf16(kf0, qf0, zero, 0, 0, 0);
        st[kc]   = __builtin_amdgcn_mfma_f32_16x16x32_bf16(kf1, qf1, s, 0, 0, 0);
    }
    // exp2, partial row sums, pack -> wave-private P LDS [q][kv]
#pragma unroll
    for (int kc = 0; kc < 4; ++kc) {
        float e0, e1, e2, e3;
#pragma unroll
        for (int r = 0; r < 4; ++r) {
            float v = st[kc][r];
            if (MASK && (kv0 + kc * 16 + quad * 4 + r > qcol)) v = -1e30f;
            float e = __builtin_amdgcn_exp2f(v);
            ls[r] += e;
            if (r == 0) e0 = e; else if (r == 1) e1 = e; else if (r == 2) e2 = e; else e3 = e;
        }
        uint2 pk; pk.x = pk_bf16(e0, e1); pk.y = pk_bf16(e2, e3);
        *(uint2*)&pb[m * PSTRIDE + kc * 16 + quad * 4] = pk;
    }
    // PV: O^T += V^T-frag x P^T-frag; V frags from swizzled LDS
#pragma unroll
    for (int ks = 0; ks < 2; ++ks) {
        bf16x8 pf = *(const bf16x8*)&pb[m * PSTRIDE + ks * 32 + quad * 8];
#pragma unroll
        for (int dg = 0; dg < 4; ++dg) {
            int rr = dg * 16 + m;
            bf16x8 vfr = *(const bf16x8*)&Vs[rr * 64 + (((quad + 4 * ks) ^ sw) << 3)];
            o[dg] = __builtin_amdgcn_mfma_f32_16x16x32_bf16(vfr, pf, o[dg], 0, 0, 0);
        }
    }
}

__global__ __launch_bounds__(256) void attn_kernel(
    const u16* __restrict__ Q, const u16* __restrict__ K,
    const u16* __restrict__ Vt, u16* __restrict__ Y)
{
    __shared__ u16 Ks[64 * 64];
    __shared__ u16 Vs[64 * 64];
    __shared__ u16 Pl[4][16 * PSTRIDE];
    int t = threadIdx.x;
    int w = t >> 6, lane = t & 63;
    int m = lane & 15, quad = lane >> 4;

    int bid = blockIdx.x;
    int head = bid & 31;                 // head%8 = bid%8 -> XCD affinity
    int g = bid >> 5;                    // 0..15
    int pr = (g < 8) ? g : 23 - g;       // co-resident pair (bid, bid+256) sums const
    int qbA = pr;                        // light q-block (chunks 0..qbA)
    int qbB = 31 - pr;                   // heavy q-block (chunks 0..qbB)
    int rowA = qbA * 64 + w * 16;
    int rowB = qbB * 64 + w * 16;

    const u16* qpA = Q + ((size_t)head * TT + rowA + m) * HDD + quad * 8;
    const u16* qpB = Q + ((size_t)head * TT + rowB + m) * HDD + quad * 8;
    bf16x8 qA0 = *(const bf16x8*)qpA;
    bf16x8 qA1 = *(const bf16x8*)(qpA + 32);
    bf16x8 qB0 = *(const bf16x8*)qpB;
    bf16x8 qB1 = *(const bf16x8*)(qpB + 32);

    const u16* kbase = K + (size_t)head * TT * HDD;   // [t][d]
    const u16* vbase = Vt + (size_t)head * HDD * TT;  // [d][t]
    u16* pb = &Pl[w][0];

    // staging geometry (lane-contiguous LDS, XOR swizzle on global col-group)
    int lr = lane >> 3;
    int cg = (lane & 7) ^ lr;
    int r0 = w * 16 + lr, r1 = r0 + 8;
    u16* ldsK0 = Ks + (size_t)(w * 128 + lane) * 8;
    u16* ldsK1 = Ks + (size_t)(w * 128 + 64 + lane) * 8;
    u16* ldsV0 = Vs + (size_t)(w * 128 + lane) * 8;
    u16* ldsV1 = Vs + (size_t)(w * 128 + 64 + lane) * 8;

    f32x4 zero = {0.f, 0.f, 0.f, 0.f};
    f32x4 oA[4], oB[4], lsA = zero, lsB = zero;
#pragma unroll
    for (int dg = 0; dg < 4; ++dg) { oA[dg] = zero; oB[dg] = zero; }
    int qcolA = rowA + m, qcolB = rowB + m;

    for (int ic = 0; ic <= qbB; ++ic) {
        int kv0 = ic << 6;
        async_copy16(kbase + (size_t)(kv0 + r0) * 64 + cg * 8, ldsK0);
        async_copy16(kbase + (size_t)(kv0 + r1) * 64 + cg * 8, ldsK1);
        async_copy16(vbase + (size_t)r0 * TT + kv0 + cg * 8, ldsV0);
        async_copy16(vbase + (size_t)r1 * TT + kv0 + cg * 8, ldsV1);
        __syncthreads();            // staged chunk arrived
        if (ic < qbA)
            tile_compute<false>(Ks, Vs, pb, qA0, qA1, m, quad, qcolA, kv0, oA, lsA);
        else if (ic == qbA)
            tile_compute<true>(Ks, Vs, pb, qA0, qA1, m, quad, qcolA, kv0, oA, lsA);
        if (ic < qbB)
            tile_compute<false>(Ks, Vs, pb, qB0, qB1, m, quad, qcolB, kv0, oB, lsB);
        else
            tile_compute<true>(Ks, Vs, pb, qB0, qB1, m, quad, qcolB, kv0, oB, lsB);
        __syncthreads();            // all waves done before restage
    }

    // row-sum reduce (q on lane&15; partials across quad groups)
    float lA = (lsA[0] + lsA[1]) + (lsA[2] + lsA[3]);
    float lB = (lsB[0] + lsB[1]) + (lsB[2] + lsB[3]);
    lA += __shfl_xor(lA, 16, 64); lA += __shfl_xor(lA, 32, 64);
    lB += __shfl_xor(lB, 16, 64); lB += __shfl_xor(lB, 32, 64);
    float invA = 1.0f / lA, invB = 1.0f / lB;

    int b = head >> 4, h = head & 15;
    size_t roA = ((size_t)(b * TT + rowA + m)) * CCH + h * HDD;
    size_t roB = ((size_t)(b * TT + rowB + m)) * CCH + h * HDD;
#pragma unroll
    for (int dg = 0; dg < 4; ++dg) {
        uint2 ov;
        ov.x = pk_bf16(oA[dg][0] * invA, oA[dg][1] * invA);
        ov.y = pk_bf16(oA[dg][2] * invA, oA[dg][3] * invA);
        *(uint2*)&Y[roA + dg * 16 + quad * 4] = ov;
        ov.x = pk_bf16(oB[dg][0] * invB, oB[dg][1] * invB);
        ov.y = pk_bf16(oB[dg][2] * invB, oB[dg][3] * invB);
        *(uint2*)&Y[roB + dg * 16 + quad * 4] = ov;
    }
}

// ---------------- launch ----------------

extern "C" void kernel_launch(void* const* d_in, const int* in_sizes, int n_in,
                              void* d_out, int out_size, void* d_ws, size_t ws_size,
                              hipStream_t stream) {
    const float* x      = (const float*)d_in[0];
    const float* w_attn = (const float*)d_in[1];
    const float* w_proj = (const float*)d_in[2];
    float* out = (float*)d_out;

    char* ws = (char*)d_ws;
    u16* x_bf   = (u16*)ws; ws += (size_t)M_TOK * CCH * 2;         // 8 MB
    u16* wqkvT  = (u16*)ws; ws += (size_t)N_QKV * CCH * 2;         // 6 MB
    u16* wprojT = (u16*)ws; ws += (size_t)CCH * CCH * 2;           // 2 MB
    u16* qbuf   = (u16*)ws; ws += (size_t)BB * NHH * TT * HDD * 2; // 8 MB
    u16* kbuf   = (u16*)ws; ws += (size_t)BB * NHH * TT * HDD * 2; // 8 MB
    u16* vtb    = (u16*)ws; ws += (size_t)BB * NHH * HDD * TT * 2; // 8 MB
    u16* yb     = (u16*)ws; ws += (size_t)M_TOK * CCH * 2;         // 8 MB

    // softmax scale * log2(e), folded into Q columns of w_attn during transpose
    const float QSC = 0.125f * 1.44269504088896f;

    // 1. cast x -> bf16
    cast_bf16_kernel<<<dim3(M_TOK * CCH / 4 / 256), dim3(256), 0, stream>>>(x, x_bf, M_TOK * CCH / 4);
    // 2. transpose weights -> bf16 [N][K]
    transpose_bf16_kernel<<<dim3(N_QKV / 32, CCH / 32), dim3(32, 8), 0, stream>>>(
        w_attn, wqkvT, CCH, N_QKV, CCH, QSC);
    transpose_bf16_kernel<<<dim3(CCH / 32, CCH / 32), dim3(32, 8), 0, stream>>>(
        w_proj, wprojT, CCH, CCH, 0, 1.0f);
    // 3. merged QKV GEMM: 768 blocks (3/CU), dual-orientation epilogue
    qkv_gemm_kernel<<<dim3(24, 32), dim3(256), 0, stream>>>(
        x_bf, wqkvT, qbuf, kbuf, vtb);
    // 4. flash attention v9 (unchanged)
    attn_kernel<<<dim3(512), dim3(256), 0, stream>>>(qbuf, kbuf, vtb, yb);
    // 5. output projection: 128x64 tiles, 512 blocks (2/CU)
    proj_gemm_kernel<<<dim3(16, 32), dim3(256), 0, stream>>>(yb, wprojT, out);
}

// Round 11
// 177.821 us; speedup vs baseline: 1.2007x; 1.1064x over previous
//
#include <hip/hip_runtime.h>
#include <hip/hip_bf16.h>

#define BB 2
#define TT 2048
#define CCH 1024
#define NHH 16
#define HDD 64
#define M_TOK (BB*TT)      // 4096
#define N_QKV (3*CCH)      // 3072

typedef __attribute__((ext_vector_type(8))) short bf16x8;
typedef __attribute__((ext_vector_type(4))) float f32x4;
typedef unsigned short u16;
typedef unsigned int u32;

__device__ __forceinline__ u16 f2bf(float f) {
    union { float f; u32 u; } v; v.f = f;
    u32 u = v.u;
    u32 r = (u + 0x7FFFu + ((u >> 16) & 1u)) >> 16;
    return (u16)r;
}

// pack hi16(a),hi16(b) -> u32 {b.hi<<16 | a.hi} with +0x8000 rounding
__device__ __forceinline__ u32 pk_bf16(float a, float b) {
    u32 ua = __float_as_uint(a) + 0x8000u;
    u32 ub = __float_as_uint(b) + 0x8000u;
    return __builtin_amdgcn_perm(ub, ua, 0x07060302u);
}

__device__ __forceinline__ void async_copy16(const void* g, void* l) {
    __builtin_amdgcn_global_load_lds((__attribute__((address_space(1))) void*)g,
                                     (__attribute__((address_space(3))) void*)l,
                                     16, 0, 0);
}

// ---------------- pre-pass kernels ----------------

__global__ __launch_bounds__(256) void cast_bf16_kernel(
    const float* __restrict__ src, u16* __restrict__ dst, int n4) {
    int i = blockIdx.x * 256 + threadIdx.x;
    if (i < n4) {
        float4 f = ((const float4*)src)[i];
        ushort4 o;
        o.x = f2bf(f.x); o.y = f2bf(f.y); o.z = f2bf(f.z); o.w = f2bf(f.w);
        ((ushort4*)dst)[i] = o;
    }
}

// src [R][Cn] fp32 -> dst [Cn][R] bf16; rows of dst with index < scale_rows get *= sc
__global__ __launch_bounds__(256) void transpose_bf16_kernel(
    const float* __restrict__ src, u16* __restrict__ dst, int R, int Cn,
    int scale_rows, float sc) {
    __shared__ float tile[32][33];
    int c0 = blockIdx.x * 32, r0 = blockIdx.y * 32;
    int tx = threadIdx.x, ty = threadIdx.y;
#pragma unroll
    for (int i = ty; i < 32; i += 8)
        tile[i][tx] = src[(size_t)(r0 + i) * Cn + c0 + tx];
    __syncthreads();
#pragma unroll
    for (int i = ty; i < 32; i += 8) {
        float v = tile[tx][i];
        if (c0 + i < scale_rows) v *= sc;
        dst[(size_t)(c0 + i) * R + r0 + tx] = f2bf(v);
    }
}

// ---------------- shared GEMM K-loop, BK=64, XOR-swizzled LDS ----------------
// A[M][K] x Bt[N][K]^T. M-tile 128, N-tile NJ*32 (NJ=4 -> 128, NJ=2 -> 64).
// LDS rows [row][64] with 16B chunk c stored at c ^ (row&7)  (swizzle applied
// on the GLOBAL address during global_load_lds staging; lane-contiguous LDS).
// Fragment ds_read_b128 then hits all 32 banks with exactly 2 lanes/bank (free).
// SWAP=1: mfma(B,A) -> acc holds C^T fragment (token on lane&15, cols on regs).

template<int SWAP, int NJ>
__device__ __forceinline__ void gemm_kloop64(
    const u16* __restrict__ A, const u16* __restrict__ Bt, int K,
    int m0, int n0, int t, u16* __restrict__ As, u16* __restrict__ Bs,
    f32x4 (&acc)[4][4])
{
    int lane = t & 63, w = t >> 6;
    int mw = (w >> 1) * 64, nw = (w & 1) * (NJ * 16);
    int mr = lane & 15, quad = lane >> 4;
    int lr = lane >> 3;                 // row-in-group 0..7
    int cswz = (lane & 7) ^ lr;         // swizzled 16B-chunk on the global side

    const u16* gA[4]; u16* lA[4];
#pragma unroll
    for (int p = 0; p < 4; ++p) {
        int grp = w * 4 + p;            // 16 groups x 8 rows = 128
        gA[p] = A + (size_t)(m0 + grp * 8 + lr) * K + cswz * 8;
        lA[p] = As + ((size_t)grp * 64 + lane) * 8;
    }
    const u16* gB[4]; u16* lB[4];
#pragma unroll
    for (int p = 0; p < NJ; ++p) {
        int grp = w * NJ + p;           // NJ groups per wave
        gB[p] = Bt + (size_t)(n0 + grp * 8 + lr) * K + cswz * 8;
        lB[p] = Bs + ((size_t)grp * 64 + lane) * 8;
    }

    int swm = mr & 7;
    for (int k0 = 0; k0 < K; k0 += 64) {
#pragma unroll
        for (int p = 0; p < 4; ++p) async_copy16(gA[p] + k0, lA[p]);
#pragma unroll
        for (int p = 0; p < NJ; ++p) async_copy16(gB[p] + k0, lB[p]);
        __syncthreads();
#pragma unroll
        for (int kk = 0; kk < 2; ++kk) {
            bf16x8 af[4], bfr[4];
#pragma unroll
            for (int i = 0; i < 4; ++i) {
                int r = mw + i * 16 + mr;
                af[i] = *(const bf16x8*)&As[r * 64 + (((kk * 4 + quad) ^ swm) << 3)];
            }
#pragma unroll
            for (int j = 0; j < NJ; ++j) {
                int r = nw + j * 16 + mr;
                bfr[j] = *(const bf16x8*)&Bs[r * 64 + (((kk * 4 + quad) ^ swm) << 3)];
            }
#pragma unroll
            for (int i = 0; i < 4; ++i)
#pragma unroll
                for (int j = 0; j < NJ; ++j) {
                    if (SWAP)
                        acc[i][j] = __builtin_amdgcn_mfma_f32_16x16x32_bf16(bfr[j], af[i], acc[i][j], 0, 0, 0);
                    else
                        acc[i][j] = __builtin_amdgcn_mfma_f32_16x16x32_bf16(af[i], bfr[j], acc[i][j], 0, 0, 0);
                }
        }
        __syncthreads();
    }
}

// ---------------- merged QKV GEMM: one 768-block dispatch ----------------
// Parts 0/1 (Q/K): swapped loop -> [bh][t][d] bf16, 8B stores along d.
// Part 2 (V): normal loop -> Vt [bh][d][t] bf16, 8B stores along t.

__global__ __launch_bounds__(256, 3) void qkv_gemm_kernel(
    const u16* __restrict__ A, const u16* __restrict__ Bt,
    u16* __restrict__ Qo, u16* __restrict__ Ko, u16* __restrict__ Vto)
{
    __shared__ u16 As[128 * 64];
    __shared__ u16 Bs[128 * 64];
    int t = threadIdx.x;
    int m0 = blockIdx.y * 128, n0 = blockIdx.x * 128;
    int part = n0 >> 10;
    int lane = t & 63, w = t >> 6;
    int mw = (w >> 1) * 64, nw = (w & 1) * 64;
    int mr = lane & 15, quad = lane >> 4;

    f32x4 zero = {0.f, 0.f, 0.f, 0.f};
    f32x4 acc[4][4];
#pragma unroll
    for (int i = 0; i < 4; ++i)
#pragma unroll
        for (int j = 0; j < 4; ++j) acc[i][j] = zero;

    if (part < 2) {   // block-uniform branch
        gemm_kloop64<1, 4>(A, Bt, CCH, m0, n0, t, As, Bs, acc);
        u16* dstp = part ? Ko : Qo;
#pragma unroll
        for (int i = 0; i < 4; ++i)
#pragma unroll
            for (int j = 0; j < 4; ++j) {
                int tok = m0 + mw + i * 16 + mr;
                int cg0 = n0 + nw + j * 16 + quad * 4;
                int cc = cg0 & 1023;
                int h = cc >> 6, d0 = cc & 63;
                int b = tok >> 11, tt = tok & 2047;
                int bh = b * NHH + h;
                uint2 o;
                o.x = pk_bf16(acc[i][j][0], acc[i][j][1]);
                o.y = pk_bf16(acc[i][j][2], acc[i][j][3]);
                *(uint2*)&dstp[((size_t)bh * TT + tt) * HDD + d0] = o;
            }
    } else {
        gemm_kloop64<0, 4>(A, Bt, CCH, m0, n0, t, As, Bs, acc);
#pragma unroll
        for (int i = 0; i < 4; ++i)
#pragma unroll
            for (int j = 0; j < 4; ++j) {
                int t0 = m0 + mw + i * 16 + quad * 4;
                int cg = n0 + nw + j * 16 + mr;
                int cc = cg & 1023;
                int h = cc >> 6, d = cc & 63;
                int b = t0 >> 11, tt0 = t0 & 2047;
                int bh = b * NHH + h;
                uint2 o;
                o.x = pk_bf16(acc[i][j][0], acc[i][j][1]);
                o.y = pk_bf16(acc[i][j][2], acc[i][j][3]);
                *(uint2*)&Vto[((size_t)bh * HDD + d) * TT + tt0] = o;
            }
    }
}

// ---------------- output projection: 128x64 tiles, 512 blocks (2/CU) ----------------

__global__ __launch_bounds__(256) void proj_gemm_kernel(
    const u16* __restrict__ A, const u16* __restrict__ Bt, float* __restrict__ Cout)
{
    __shared__ u16 As[128 * 64];
    __shared__ u16 Bs[64 * 64];
    int t = threadIdx.x;
    int m0 = blockIdx.y * 128, n0 = blockIdx.x * 64;
    int lane = t & 63, w = t >> 6;
    int mw = (w >> 1) * 64, nw = (w & 1) * 32;
    int mr = lane & 15, quad = lane >> 4;

    f32x4 zero = {0.f, 0.f, 0.f, 0.f};
    f32x4 acc[4][4];
#pragma unroll
    for (int i = 0; i < 4; ++i)
#pragma unroll
        for (int j = 0; j < 4; ++j) acc[i][j] = zero;

    gemm_kloop64<1, 2>(A, Bt, CCH, m0, n0, t, As, Bs, acc);

#pragma unroll
    for (int i = 0; i < 4; ++i)
#pragma unroll
        for (int j = 0; j < 2; ++j) {
            int tok = m0 + mw + i * 16 + mr;
            int cg0 = n0 + nw + j * 16 + quad * 4;
            float4 v;
            v.x = acc[i][j][0]; v.y = acc[i][j][1];
            v.z = acc[i][j][2]; v.w = acc[i][j][3];
            *(float4*)&Cout[(size_t)tok * CCH + cg0] = v;
        }
}

// ---------------- flash attention v10 ----------------
// = v9 structure (single-buffered K+V LDS, 2 barriers/chunk, balanced pairing,
//   cheap softmax) + HOISTED K/V fragment loads shared by both paired tiles:
// 16 b128 fragment reads once per chunk instead of twice (DS ops 44->28/wave).

#define PSTRIDE 72

template<bool MASK>
__device__ __forceinline__ void tile_compute(
    const bf16x8 (&kf)[4][2], const bf16x8 (&vf)[4][2], u16* __restrict__ pb,
    bf16x8 qf0, bf16x8 qf1, int m, int quad, int qcol, int kv0,
    f32x4 (&o)[4], f32x4& ls)
{
    f32x4 zero = {0.f, 0.f, 0.f, 0.f};
    // QK^T -> S^T: kv on quad*4+r (per kc), q on lane&15
    f32x4 st[4];
#pragma unroll
    for (int kc = 0; kc < 4; ++kc) {
        f32x4 s = __builtin_amdgcn_mfma_f32_16x16x32_bf16(kf[kc][0], qf0, zero, 0, 0, 0);
        st[kc]   = __builtin_amdgcn_mfma_f32_16x16x32_bf16(kf[kc][1], qf1, s, 0, 0, 0);
    }
    // exp2, partial row sums, pack -> wave-private P LDS [q][kv]
#pragma unroll
    for (int kc = 0; kc < 4; ++kc) {
        float e0, e1, e2, e3;
#pragma unroll
        for (int r = 0; r < 4; ++r) {
            float v = st[kc][r];
            if (MASK && (kv0 + kc * 16 + quad * 4 + r > qcol)) v = -1e30f;
            float e = __builtin_amdgcn_exp2f(v);
            ls[r] += e;
            if (r == 0) e0 = e; else if (r == 1) e1 = e; else if (r == 2) e2 = e; else e3 = e;
        }
        uint2 pk; pk.x = pk_bf16(e0, e1); pk.y = pk_bf16(e2, e3);
        *(uint2*)&pb[m * PSTRIDE + kc * 16 + quad * 4] = pk;
    }
    // PV: O^T += V^T-frag x P^T-frag
#pragma unroll
    for (int ks = 0; ks < 2; ++ks) {
        bf16x8 pf = *(const bf16x8*)&pb[m * PSTRIDE + ks * 32 + quad * 8];
#pragma unroll
        for (int dg = 0; dg < 4; ++dg)
            o[dg] = __builtin_amdgcn_mfma_f32_16x16x32_bf16(vf[dg][ks], pf, o[dg], 0, 0, 0);
    }
}

__global__ __launch_bounds__(256) void attn_kernel(
    const u16* __restrict__ Q, const u16* __restrict__ K,
    const u16* __restrict__ Vt, u16* __restrict__ Y)
{
    __shared__ u16 Ks[64 * 64];
    __shared__ u16 Vs[64 * 64];
    __shared__ u16 Pl[4][16 * PSTRIDE];
    int t = threadIdx.x;
    int w = t >> 6, lane = t & 63;
    int m = lane & 15, quad = lane >> 4;

    int bid = blockIdx.x;
    int head = bid & 31;                 // head%8 = bid%8 -> XCD affinity
    int g = bid >> 5;                    // 0..15
    int pr = (g < 8) ? g : 23 - g;       // co-resident pair (bid, bid+256) sums const
    int qbA = pr;                        // light q-block (chunks 0..qbA)
    int qbB = 31 - pr;                   // heavy q-block (chunks 0..qbB)
    int rowA = qbA * 64 + w * 16;
    int rowB = qbB * 64 + w * 16;

    const u16* qpA = Q + ((size_t)head * TT + rowA + m) * HDD + quad * 8;
    const u16* qpB = Q + ((size_t)head * TT + rowB + m) * HDD + quad * 8;
    bf16x8 qA0 = *(const bf16x8*)qpA;
    bf16x8 qA1 = *(const bf16x8*)(qpA + 32);
    bf16x8 qB0 = *(const bf16x8*)qpB;
    bf16x8 qB1 = *(const bf16x8*)(qpB + 32);

    const u16* kbase = K + (size_t)head * TT * HDD;   // [t][d]
    const u16* vbase = Vt + (size_t)head * HDD * TT;  // [d][t]
    u16* pb = &Pl[w][0];

    // staging geometry (lane-contiguous LDS, XOR swizzle on global col-group)
    int lr = lane >> 3;
    int cg = (lane & 7) ^ lr;
    int r0 = w * 16 + lr, r1 = r0 + 8;
    u16* ldsK0 = Ks + (size_t)(w * 128 + lane) * 8;
    u16* ldsK1 = Ks + (size_t)(w * 128 + 64 + lane) * 8;
    u16* ldsV0 = Vs + (size_t)(w * 128 + lane) * 8;
    u16* ldsV1 = Vs + (size_t)(w * 128 + 64 + lane) * 8;

    f32x4 zero = {0.f, 0.f, 0.f, 0.f};
    f32x4 oA[4], oB[4], lsA = zero, lsB = zero;
#pragma unroll
    for (int dg = 0; dg < 4; ++dg) { oA[dg] = zero; oB[dg] = zero; }
    int qcolA = rowA + m, qcolB = rowB + m;
    int sw = m & 7;

    for (int ic = 0; ic <= qbB; ++ic) {
        int kv0 = ic << 6;
        async_copy16(kbase + (size_t)(kv0 + r0) * 64 + cg * 8, ldsK0);
        async_copy16(kbase + (size_t)(kv0 + r1) * 64 + cg * 8, ldsK1);
        async_copy16(vbase + (size_t)r0 * TT + kv0 + cg * 8, ldsV0);
        async_copy16(vbase + (size_t)r1 * TT + kv0 + cg * 8, ldsV1);
        __syncthreads();            // staged chunk arrived
        // hoisted fragment loads, shared by both paired tiles
        bf16x8 kf[4][2], vf[4][2];
#pragma unroll
        for (int kc = 0; kc < 4; ++kc) {
            int rr = kc * 16 + m;
            kf[kc][0] = *(const bf16x8*)&Ks[rr * 64 + ((quad ^ sw) << 3)];
            kf[kc][1] = *(const bf16x8*)&Ks[rr * 64 + (((quad + 4) ^ sw) << 3)];
            vf[kc][0] = *(const bf16x8*)&Vs[rr * 64 + ((quad ^ sw) << 3)];
            vf[kc][1] = *(const bf16x8*)&Vs[rr * 64 + (((quad + 4) ^ sw) << 3)];
        }
        if (ic < qbA)
            tile_compute<false>(kf, vf, pb, qA0, qA1, m, quad, qcolA, kv0, oA, lsA);
        else if (ic == qbA)
            tile_compute<true>(kf, vf, pb, qA0, qA1, m, quad, qcolA, kv0, oA, lsA);
        if (ic < qbB)
            tile_compute<false>(kf, vf, pb, qB0, qB1, m, quad, qcolB, kv0, oB, lsB);
        else
            tile_compute<true>(kf, vf, pb, qB0, qB1, m, quad, qcolB, kv0, oB, lsB);
        __syncthreads();            // all waves done before restage
    }

    // row-sum reduce (q on lane&15; partials across quad groups)
    float lA = (lsA[0] + lsA[1]) + (lsA[2] + lsA[3]);
    float lB = (lsB[0] + lsB[1]) + (lsB[2] + lsB[3]);
    lA += __shfl_xor(lA, 16, 64); lA += __shfl_xor(lA, 32, 64);
    lB += __shfl_xor(lB, 16, 64); lB += __shfl_xor(lB, 32, 64);
    float invA = 1.0f / lA, invB = 1.0f / lB;

    int b = head >> 4, h = head & 15;
    size_t roA = ((size_t)(b * TT + rowA + m)) * CCH + h * HDD;
    size_t roB = ((size_t)(b * TT + rowB + m)) * CCH + h * HDD;
#pragma unroll
    for (int dg = 0; dg < 4; ++dg) {
        uint2 ov;
        ov.x = pk_bf16(oA[dg][0] * invA, oA[dg][1] * invA);
        ov.y = pk_bf16(oA[dg][2] * invA, oA[dg][3] * invA);
        *(uint2*)&Y[roA + dg * 16 + quad * 4] = ov;
        ov.x = pk_bf16(oB[dg][0] * invB, oB[dg][1] * invB);
        ov.y = pk_bf16(oB[dg][2] * invB, oB[dg][3] * invB);
        *(uint2*)&Y[roB + dg * 16 + quad * 4] = ov;
    }
}

// ---------------- launch ----------------

extern "C" void kernel_launch(void* const* d_in, const int* in_sizes, int n_in,
                              void* d_out, int out_size, void* d_ws, size_t ws_size,
                              hipStream_t stream) {
    const float* x      = (const float*)d_in[0];
    const float* w_attn = (const float*)d_in[1];
    const float* w_proj = (const float*)d_in[2];
    float* out = (float*)d_out;

    char* ws = (char*)d_ws;
    u16* x_bf   = (u16*)ws; ws += (size_t)M_TOK * CCH * 2;         // 8 MB
    u16* wqkvT  = (u16*)ws; ws += (size_t)N_QKV * CCH * 2;         // 6 MB
    u16* wprojT = (u16*)ws; ws += (size_t)CCH * CCH * 2;           // 2 MB
    u16* qbuf   = (u16*)ws; ws += (size_t)BB * NHH * TT * HDD * 2; // 8 MB
    u16* kbuf   = (u16*)ws; ws += (size_t)BB * NHH * TT * HDD * 2; // 8 MB
    u16* vtb    = (u16*)ws; ws += (size_t)BB * NHH * HDD * TT * 2; // 8 MB
    u16* yb     = (u16*)ws; ws += (size_t)M_TOK * CCH * 2;         // 8 MB

    // softmax scale * log2(e), folded into Q columns of w_attn during transpose
    const float QSC = 0.125f * 1.44269504088896f;

    // 1. cast x -> bf16
    cast_bf16_kernel<<<dim3(M_TOK * CCH / 4 / 256), dim3(256), 0, stream>>>(x, x_bf, M_TOK * CCH / 4);
    // 2. transpose weights -> bf16 [N][K]
    transpose_bf16_kernel<<<dim3(N_QKV / 32, CCH / 32), dim3(32, 8), 0, stream>>>(
        w_attn, wqkvT, CCH, N_QKV, CCH, QSC);
    transpose_bf16_kernel<<<dim3(CCH / 32, CCH / 32), dim3(32, 8), 0, stream>>>(
        w_proj, wprojT, CCH, CCH, 0, 1.0f);
    // 3. merged QKV GEMM: 768 blocks (3/CU), BK=64, swizzled LDS
    qkv_gemm_kernel<<<dim3(24, 32), dim3(256), 0, stream>>>(
        x_bf, wqkvT, qbuf, kbuf, vtb);
    // 4. flash attention v10 (hoisted shared K/V fragments)
    attn_kernel<<<dim3(512), dim3(256), 0, stream>>>(qbuf, kbuf, vtb, yb);
    // 5. output projection: 128x64 tiles, BK=64, 512 blocks (2/CU)
    proj_gemm_kernel<<<dim3(16, 32), dim3(256), 0, stream>>>(yb, wprojT, out);
}